// Round 1
// baseline (125.814 us; speedup 1.0000x reference)
//
#include <hip/hip_runtime.h>
#include <hip/hip_bf16.h>
#include <math.h>

#define Bn 8
#define Tn 2048
#define Cn 1024
#define Hn 64

typedef __attribute__((ext_vector_type(8))) short short8;
typedef __attribute__((ext_vector_type(4))) float floatx4;

#define ATTN_SCALE 0.18033688011112042f   // log2(e) / sqrt(64)

__device__ inline unsigned short f2bf(float f) {
    union { float f; unsigned int u; } x; x.f = f;
    unsigned int r = x.u + 0x7fffu + ((x.u >> 16) & 1u);
    return (unsigned short)(r >> 16);
}

__device__ inline uint2 pack4bf(float4 v) {
    __hip_bfloat162 lo = __float22bfloat162_rn(make_float2(v.x, v.y));
    __hip_bfloat162 hi = __float22bfloat162_rn(make_float2(v.z, v.w));
    uint2 r;
    r.x = *reinterpret_cast<unsigned int*>(&lo);
    r.y = *reinterpret_cast<unsigned int*>(&hi);
    return r;
}

__device__ inline float rsum16(float v) {
    v += __shfl_xor(v, 1);
    v += __shfl_xor(v, 2);
    v += __shfl_xor(v, 4);
    v += __shfl_xor(v, 8);
    return v;
}

// ---------------------------------------------------------------------------
// Kernel 0: W -> bf16 in MFMA B-FRAGMENT ORDER.  (unchanged, verified)
// ---------------------------------------------------------------------------
__global__ __launch_bounds__(256) void prep_w(
    const float* __restrict__ Wq, const float* __restrict__ Wk,
    const float* __restrict__ Wv, unsigned short* __restrict__ Wfrag)
{
    const int gid = blockIdx.x * 256 + threadIdx.x;   // 0..24575
    const int c    = gid >> 11;
    const int rem  = gid & 2047;
    const int ks   = rem >> 6;
    const int lane = rem & 63;
    const int ln = lane & 15, qd = lane >> 4;
    const int mat = c >> 2, nc = c & 3;
    const float* W = (mat == 0) ? Wq : (mat == 1) ? Wk : Wv;
    const float sc = (mat == 0) ? ATTN_SCALE : 1.0f;
    const int col = nc * 16 + ln;
    unsigned short o[8];
    #pragma unroll
    for (int j = 0; j < 8; ++j)
        o[j] = f2bf(W[(size_t)(ks * 32 + qd * 8 + j) * Hn + col] * sc);
    *reinterpret_cast<short8*>(Wfrag + (size_t)gid * 8) = *reinterpret_cast<short8*>(o);
}

// ---------------------------------------------------------------------------
// Kernel 1: fused QKV projection — 32 ROWS/BLOCK (2 row-tiles), full-K stage.
// 512 blocks x 4 waves, 2 blocks/CU (64 KB LDS), ONE barrier.
// Each B-fragment load (L2) now feeds TWO MFMAs -> L2 B-traffic halves
// (402 -> 197 MB); 2 resident blocks/CU overlap stage (HBM) with compute (L2).
// Frag layout per row-tile rt: xs[(s*2+rt)*512 + (q*16+rr)*8 + j], identical
// element math to the verified 16-row kernel.
// ---------------------------------------------------------------------------
__global__ __launch_bounds__(256, 2) void proj_mfma(
    const float* __restrict__ x, const unsigned short* __restrict__ Wfrag,
    unsigned short* __restrict__ qbf, unsigned short* __restrict__ kfrag,
    unsigned short* __restrict__ vfrag)
{
    __shared__ unsigned short xs[64 * 512];     // 64 KB

    const int ln   = threadIdx.x & 15;
    const int quad = (threadIdx.x >> 4) & 3;
    const int w    = threadIdx.x >> 6;
    const int lane = threadIdx.x & 63;
    const int row0 = blockIdx.x * 32;

    const int srow = threadIdx.x >> 4;          // 0..15
    const int sf   = threadIdx.x & 15;          // f4 slot base

    // ---- phase 1: stage 32x1024 x-tile, 4 batches of 8 float4 loads ----
    #pragma unroll
    for (int bb = 0; bb < 4; ++bb) {
        const int row = srow + 16 * (bb >> 1);
        const float4* xrow4 = reinterpret_cast<const float4*>(x + (size_t)(row0 + row) * Cn);
        float4 ld[8];
        #pragma unroll
        for (int it = 0; it < 8; ++it)
            ld[it] = xrow4[sf + 16 * (it + 8 * (bb & 1))];
        const int rt = row >> 4;
        const int rr = row & 15;
        #pragma unroll
        for (int it = 0; it < 8; ++it) {
            const int f4 = sf + 16 * (it + 8 * (bb & 1));
            const int s  = f4 >> 3;
            const int q  = (f4 >> 1) & 3;
            const int jj = (f4 & 1) * 4;
            *reinterpret_cast<uint2*>(&xs[(s * 2 + rt) * 512 + (q * 16 + rr) * 8 + jj])
                = pack4bf(ld[it]);
        }
    }
    __syncthreads();

    // ---- phase 2: barrier-free MFMA stream, B-frag reused across 2 row-tiles
    floatx4 acc[2][3];
    #pragma unroll
    for (int rt = 0; rt < 2; ++rt)
        #pragma unroll
        for (int i = 0; i < 3; ++i) acc[rt][i] = (floatx4){0.f, 0.f, 0.f, 0.f};

    #pragma unroll 4
    for (int s = 0; s < 32; ++s) {
        const short8 a0 = *reinterpret_cast<const short8*>(&xs[(s * 2 + 0) * 512 + lane * 8]);
        const short8 a1 = *reinterpret_cast<const short8*>(&xs[(s * 2 + 1) * 512 + lane * 8]);
        #pragma unroll
        for (int i = 0; i < 3; ++i) {
            const int cc = w * 3 + i;
            const short8 b = *reinterpret_cast<const short8*>(
                Wfrag + ((size_t)(cc * 32 + s) * 64 + lane) * 8);
            acc[0][i] = __builtin_amdgcn_mfma_f32_16x16x32_bf16(a0, b, acc[0][i], 0, 0, 0);
            acc[1][i] = __builtin_amdgcn_mfma_f32_16x16x32_bf16(a1, b, acc[1][i], 0, 0, 0);
        }
    }

    // epilogue: identical math per row-tile (t0 = row0 + rt*16 + quad*4)
    #pragma unroll
    for (int rt = 0; rt < 2; ++rt) {
        const int t0   = row0 + rt * 16 + quad * 4;
        const int b    = t0 >> 11;
        const int tloc = t0 & 2047;
        #pragma unroll
        for (int i = 0; i < 3; ++i) {
            const int idx = w * 3 + i;
            const int mat = idx >> 2, ch = idx & 3;
            if (mat == 0) {
                #pragma unroll
                for (int r = 0; r < 4; ++r)
                    qbf[(size_t)(t0 + r) * Hn + ch * 16 + ln] = f2bf(acc[rt][i][r]);
            } else if (mat == 1) {
                const int kc = tloc >> 4;
                const int ks = ch >> 1;
                const int lq = (ch & 1) * 2 + (ln >> 3);
                #pragma unroll
                for (int r = 0; r < 4; ++r) {
                    const int lanep = (quad * 4 + r) + 16 * lq;
                    kfrag[(((size_t)(b * 128 + kc) * 2 + ks) * 64 + lanep) * 8 + (ln & 7)]
                        = f2bf(acc[rt][i][r]);
                }
            } else {
                const int kb32 = tloc >> 5;
                const int off  = t0 & 31;
                const int qd   = off >> 3;
                const int j0   = off & 7;
                const int lanep = ln + 16 * qd;
                ushort4 pk;
                pk.x = f2bf(acc[rt][i][0]); pk.y = f2bf(acc[rt][i][1]);
                pk.z = f2bf(acc[rt][i][2]); pk.w = f2bf(acc[rt][i][3]);
                *reinterpret_cast<ushort4*>(
                    vfrag + (((size_t)(b * 64 + kb32) * 4 + ch) * 64 + lanep) * 8 + j0) = pk;
            }
        }
    }
}

// ---------------------------------------------------------------------------
// Kernel 2: causal flash attention — 32-ROW Q-TILES, balanced pairing.
// 512 blocks (b = j&7 keeps batch->XCD pinning; working set L2-resident).
// Pairing: CU slot k gets ti = 63-2k AND ti = 2k -> per-CU work constant
// (~65 k-tiles) instead of 2:1 skew. Each K/V load feeds 2 row-tiles
// (L2 traffic 277 -> 139 MB), 16 MFMA/iter doubles ILP.
// P-tile LDS is aliased into the (later-used) O-combine buffer; same-wave
// DS ops are in-order, and the compiler sees a common base object.
// ---------------------------------------------------------------------------
__global__ __launch_bounds__(256, 2) void attn_mfma(
    const unsigned short* __restrict__ qbf, const unsigned short* __restrict__ kfrag,
    const unsigned short* __restrict__ vt, float* __restrict__ out)
{
    __shared__ float osm[4][32][68];                 // 34.8 KB (P-tile aliased in)
    __shared__ float l_lds[4][32];

    const int j  = blockIdx.x;
    const int b  = j & 7;                            // batch == XCD
    const int jj = j >> 3;                           // 0..63
    const int ti = (jj < 32) ? (63 - 2 * jj) : (2 * jj - 64);
    const int q0 = ti * 32;

    const int ln   = threadIdx.x & 15;
    const int quad = (threadIdx.x >> 4) & 3;
    const int w    = threadIdx.x >> 6;
    const int lane = threadIdx.x & 63;

    const unsigned short* qb = qbf + (size_t)b * Tn * Hn;
    const unsigned short* Kb = kfrag + (size_t)b * 131072;
    const unsigned short* Vb = vt + (size_t)b * 131072;

    short8 aq[2][2];
    #pragma unroll
    for (int rt = 0; rt < 2; ++rt) {
        aq[rt][0] = *reinterpret_cast<const short8*>(
            qb + (size_t)(q0 + rt * 16 + ln) * Hn + quad * 8);
        aq[rt][1] = *reinterpret_cast<const short8*>(
            qb + (size_t)(q0 + rt * 16 + ln) * Hn + 32 + quad * 8);
    }

    floatx4 O[2][4];
    #pragma unroll
    for (int rt = 0; rt < 2; ++rt)
        #pragma unroll
        for (int c = 0; c < 4; ++c) O[rt][c] = (floatx4){0.f, 0.f, 0.f, 0.f};
    float lp[2][4] = {{0.f, 0.f, 0.f, 0.f}, {0.f, 0.f, 0.f, 0.f}};

    const int ntiles = ti + 1;                       // 32-key tiles up to diag
    const int per    = (ntiles + 3) >> 2;
    const int beg    = w * per;
    const int end    = min(beg + per, ntiles);
    unsigned short* pP = reinterpret_cast<unsigned short*>(&osm[w][0][0]); // 2560 B used

    short8 kf[4];
    if (beg < end) {
        #pragma unroll
        for (int u = 0; u < 4; ++u)
            kf[u] = *reinterpret_cast<const short8*>(Kb + ((size_t)(beg * 4 + u)) * 512 + lane * 8);
    }

    for (int t = beg; t < end; ++t) {
        const int tn = (t + 1 < end) ? (t + 1) : t;
        short8 kn[4], vf[4];
        #pragma unroll
        for (int u = 0; u < 4; ++u) {
            kn[u] = *reinterpret_cast<const short8*>(Kb + ((size_t)(tn * 4 + u)) * 512 + lane * 8);
            vf[u] = *reinterpret_cast<const short8*>(Vb + ((size_t)(t * 4 + u)) * 512 + lane * 8);
        }

        const floatx4 z = (floatx4){0.f, 0.f, 0.f, 0.f};
        floatx4 S[2][2];
        __builtin_amdgcn_s_setprio(1);
        #pragma unroll
        for (int s = 0; s < 2; ++s) {
            #pragma unroll
            for (int rt = 0; rt < 2; ++rt) {
                S[rt][s] = __builtin_amdgcn_mfma_f32_16x16x32_bf16(aq[rt][0], kf[s * 2], z, 0, 0, 0);
                S[rt][s] = __builtin_amdgcn_mfma_f32_16x16x32_bf16(aq[rt][1], kf[s * 2 + 1], S[rt][s], 0, 0, 0);
            }
        }
        __builtin_amdgcn_s_setprio(0);

        const bool diag = (t == ntiles - 1);
        #pragma unroll
        for (int rt = 0; rt < 2; ++rt) {
            #pragma unroll
            for (int s = 0; s < 2; ++s) {
                #pragma unroll
                for (int r = 0; r < 4; ++r) {
                    float sv = S[rt][s][r];
                    if (diag && (t * 32 + s * 16 + ln > q0 + rt * 16 + quad * 4 + r)) sv = -1e30f;
                    const unsigned int pu = __float_as_uint(exp2f(sv));
                    lp[rt][r] += __uint_as_float(pu & 0xffff0000u);
                    pP[(rt * 16 + quad * 4 + r) * 40 + s * 16 + ln] = (unsigned short)(pu >> 16);
                }
            }
        }
        __asm__ volatile("s_waitcnt lgkmcnt(0)" ::: "memory");
        short8 pa[2];
        #pragma unroll
        for (int rt = 0; rt < 2; ++rt)
            pa[rt] = *reinterpret_cast<const short8*>(pP + (rt * 16 + ln) * 40 + quad * 8);
        __builtin_amdgcn_s_setprio(1);
        #pragma unroll
        for (int rt = 0; rt < 2; ++rt)
            #pragma unroll
            for (int c = 0; c < 4; ++c)
                O[rt][c] = __builtin_amdgcn_mfma_f32_16x16x32_bf16(pa[rt], vf[c], O[rt][c], 0, 0, 0);
        __builtin_amdgcn_s_setprio(0);
        #pragma unroll
        for (int u = 0; u < 4; ++u) kf[u] = kn[u];
    }

    // per-wave partials -> LDS (overwrites this wave's P region; same-wave
    // DS ordering makes that safe)
    #pragma unroll
    for (int rt = 0; rt < 2; ++rt)
        #pragma unroll
        for (int c = 0; c < 4; ++c)
            #pragma unroll
            for (int r = 0; r < 4; ++r)
                osm[w][rt * 16 + quad * 4 + r][c * 16 + ln] = O[rt][c][r];
    #pragma unroll
    for (int rt = 0; rt < 2; ++rt)
        #pragma unroll
        for (int r = 0; r < 4; ++r) {
            const float ls = rsum16(lp[rt][r]);
            if (ln == 0) l_lds[w][rt * 16 + quad * 4 + r] = ls;
        }
    __syncthreads();

    // combine: 256 threads, row qq (0..31), dims dg*8..dg*8+7
    const int qq = threadIdx.x >> 3;
    const int dg = threadIdx.x & 7;
    const float ltot = l_lds[0][qq] + l_lds[1][qq] + l_lds[2][qq] + l_lds[3][qq];
    const float inv = 1.0f / ltot;
    float* op = out + ((size_t)b * Tn + q0 + qq) * Hn + dg * 8;
    #pragma unroll
    for (int half = 0; half < 2; ++half) {
        const int d0 = dg * 8 + half * 4;
        const float4 a0 = *reinterpret_cast<const float4*>(&osm[0][qq][d0]);
        const float4 a1 = *reinterpret_cast<const float4*>(&osm[1][qq][d0]);
        const float4 a2 = *reinterpret_cast<const float4*>(&osm[2][qq][d0]);
        const float4 a3 = *reinterpret_cast<const float4*>(&osm[3][qq][d0]);
        float4 r;
        r.x = (a0.x + a1.x + a2.x + a3.x) * inv;
        r.y = (a0.y + a1.y + a2.y + a3.y) * inv;
        r.z = (a0.z + a1.z + a2.z + a3.z) * inv;
        r.w = (a0.w + a1.w + a2.w + a3.w) * inv;
        *reinterpret_cast<float4*>(op + half * 4) = r;
    }
}

// ---------------------------------------------------------------------------
extern "C" void kernel_launch(void* const* d_in, const int* in_sizes, int n_in,
                              void* d_out, int out_size, void* d_ws, size_t ws_size,
                              hipStream_t stream) {
    (void)in_sizes; (void)n_in; (void)out_size; (void)ws_size;
    const float* x  = (const float*)d_in[0];
    const float* Wq = (const float*)d_in[1];
    const float* Wk = (const float*)d_in[2];
    const float* Wv = (const float*)d_in[3];
    float* out = (float*)d_out;

    unsigned short* Wfrag = (unsigned short*)d_ws;            // 196608
    unsigned short* qbf   = Wfrag + (size_t)196608;           // 1048576
    unsigned short* kfr   = qbf + (size_t)Bn * Tn * Hn;       // 1048576
    unsigned short* vfr   = kfr + (size_t)Bn * 131072;        // 1048576

    prep_w<<<96, 256, 0, stream>>>(Wq, Wk, Wv, Wfrag);
    proj_mfma<<<(Bn * Tn) / 32, 256, 0, stream>>>(x, Wfrag, qbf, kfr, vfr);
    attn_mfma<<<Bn * (Tn / 32), 256, 0, stream>>>(qbf, kfr, vfr, out);
}

// Round 3
// 124.701 us; speedup vs baseline: 1.0089x; 1.0089x over previous
//
#include <hip/hip_runtime.h>
#include <hip/hip_bf16.h>
#include <math.h>

#define Bn 8
#define Tn 2048
#define Cn 1024
#define Hn 64

typedef __attribute__((ext_vector_type(8))) short short8;
typedef __attribute__((ext_vector_type(4))) float floatx4;

#define ATTN_SCALE 0.18033688011112042f   // log2(e) / sqrt(64)

__device__ inline unsigned short f2bf(float f) {
    union { float f; unsigned int u; } x; x.f = f;
    unsigned int r = x.u + 0x7fffu + ((x.u >> 16) & 1u);
    return (unsigned short)(r >> 16);
}

__device__ inline uint2 pack4bf(float4 v) {
    __hip_bfloat162 lo = __float22bfloat162_rn(make_float2(v.x, v.y));
    __hip_bfloat162 hi = __float22bfloat162_rn(make_float2(v.z, v.w));
    uint2 r;
    r.x = *reinterpret_cast<unsigned int*>(&lo);
    r.y = *reinterpret_cast<unsigned int*>(&hi);
    return r;
}

__device__ inline float rsum16(float v) {
    v += __shfl_xor(v, 1);
    v += __shfl_xor(v, 2);
    v += __shfl_xor(v, 4);
    v += __shfl_xor(v, 8);
    return v;
}

// ---------------------------------------------------------------------------
// Kernel 0: W -> bf16 in MFMA B-FRAGMENT ORDER.  (unchanged)
// ---------------------------------------------------------------------------
__global__ __launch_bounds__(256) void prep_w(
    const float* __restrict__ Wq, const float* __restrict__ Wk,
    const float* __restrict__ Wv, unsigned short* __restrict__ Wfrag)
{
    const int gid = blockIdx.x * 256 + threadIdx.x;   // 0..24575
    const int c    = gid >> 11;
    const int rem  = gid & 2047;
    const int ks   = rem >> 6;
    const int lane = rem & 63;
    const int ln = lane & 15, qd = lane >> 4;
    const int mat = c >> 2, nc = c & 3;
    const float* W = (mat == 0) ? Wq : (mat == 1) ? Wk : Wv;
    const float sc = (mat == 0) ? ATTN_SCALE : 1.0f;
    const int col = nc * 16 + ln;
    unsigned short o[8];
    #pragma unroll
    for (int j = 0; j < 8; ++j)
        o[j] = f2bf(W[(size_t)(ks * 32 + qd * 8 + j) * Hn + col] * sc);
    *reinterpret_cast<short8*>(Wfrag + (size_t)gid * 8) = *reinterpret_cast<short8*>(o);
}

// ---------------------------------------------------------------------------
// Kernel 1: fused QKV projection — SINGLE-STAGE LDS, BARRIER-FREE COMPUTE.
// 1024 blocks x 4 waves, 16 rows/block, 4 blocks/CU.
// Phase 1: whole 16x1024 x-tile -> LDS in A-FRAGMENT order (bf16, 32 KB),
//   fully-coalesced float4 loads, 16 in flight per thread (deep MLP).
// ONE barrier.
// Phase 2: per wave, 32 k-steps x 3 n-chunks = 96 MFMAs, zero barriers;
//   A-frag = conflict-free ds_read_b128 (lane-contiguous); B-frag = Wfrag
//   (L2-hot) lane-contiguous 16B loads.
// Frag layout: xs short-offset = s*512 + (q*16 + row)*8 + j  for element
//   x[row][k], s = k>>5, q = (k>>3)&3, j = k&7.  Reader: lane (ln+16q)
//   reads 16B at s*1024 + lane*16 bytes -> conflict-free.
// ---------------------------------------------------------------------------
__global__ __launch_bounds__(256, 4) void proj_mfma(
    const float* __restrict__ x, const unsigned short* __restrict__ Wfrag,
    unsigned short* __restrict__ qbf, unsigned short* __restrict__ kfrag,
    unsigned short* __restrict__ vfrag)
{
    __shared__ unsigned short xs[32 * 512];     // 32 KB

    const int ln   = threadIdx.x & 15;
    const int quad = (threadIdx.x >> 4) & 3;
    const int w    = threadIdx.x >> 6;
    const int lane = threadIdx.x & 63;
    const int row0 = blockIdx.x * 16;

    // ---- phase 1: stage x tile ----
    const int srow = threadIdx.x >> 4;          // 0..15
    const int sf   = threadIdx.x & 15;          // f4 slot base
    const float4* xrow4 = reinterpret_cast<const float4*>(x + (size_t)(row0 + srow) * Cn);

    float4 ld[16];
    #pragma unroll
    for (int it = 0; it < 16; ++it)
        ld[it] = xrow4[sf + 16 * it];
    #pragma unroll
    for (int it = 0; it < 16; ++it) {
        const int f4g = sf + 16 * it;
        const int s = f4g >> 3;
        const int q = (f4g >> 1) & 3;
        const int j = (f4g & 1) * 4;
        *reinterpret_cast<uint2*>(&xs[s * 512 + (q * 16 + srow) * 8 + j]) = pack4bf(ld[it]);
    }
    __syncthreads();

    // ---- phase 2: barrier-free MFMA stream ----
    floatx4 acc[3];
    #pragma unroll
    for (int i = 0; i < 3; ++i) acc[i] = (floatx4){0.f, 0.f, 0.f, 0.f};

    #pragma unroll 4
    for (int s = 0; s < 32; ++s) {
        const short8 a = *reinterpret_cast<const short8*>(&xs[s * 512 + lane * 8]);
        #pragma unroll
        for (int i = 0; i < 3; ++i) {
            const int cc = w * 3 + i;
            const short8 b = *reinterpret_cast<const short8*>(
                Wfrag + ((size_t)(cc * 32 + s) * 64 + lane) * 8);
            acc[i] = __builtin_amdgcn_mfma_f32_16x16x32_bf16(a, b, acc[i], 0, 0, 0);
        }
    }

    // epilogue: C layout col = ln, row = quad*4 + r   (round-4-verified, idx = w*3+i)
    const int t0   = row0 + quad * 4;
    const int b    = t0 >> 11;
    const int tloc = t0 & 2047;
    #pragma unroll
    for (int i = 0; i < 3; ++i) {
        const int idx = w * 3 + i;
        const int mat = idx >> 2, ch = idx & 3;
        if (mat == 0) {
            #pragma unroll
            for (int r = 0; r < 4; ++r)
                qbf[(size_t)(t0 + r) * Hn + ch * 16 + ln] = f2bf(acc[i][r]);
        } else if (mat == 1) {
            const int kc = tloc >> 4;
            const int ks = ch >> 1;
            const int lq = (ch & 1) * 2 + (ln >> 3);
            #pragma unroll
            for (int r = 0; r < 4; ++r) {
                const int lanep = (quad * 4 + r) + 16 * lq;
                kfrag[(((size_t)(b * 128 + kc) * 2 + ks) * 64 + lanep) * 8 + (ln & 7)]
                    = f2bf(acc[i][r]);
            }
        } else {
            const int kb32 = tloc >> 5;
            const int off  = t0 & 31;
            const int qd   = off >> 3;
            const int j0   = off & 7;
            const int lanep = ln + 16 * qd;
            ushort4 pk;
            pk.x = f2bf(acc[i][0]); pk.y = f2bf(acc[i][1]);
            pk.z = f2bf(acc[i][2]); pk.w = f2bf(acc[i][3]);
            *reinterpret_cast<ushort4*>(
                vfrag + (((size_t)(b * 64 + kb32) * 4 + ch) * 64 + lanep) * 8 + j0) = pk;
        }
    }
}

// ---------------------------------------------------------------------------
// Kernel 2: causal flash attention.  (byte-identical to rounds 5/6 — frozen)
// ---------------------------------------------------------------------------
__global__ __launch_bounds__(256, 4) void attn_mfma(
    const unsigned short* __restrict__ qbf, const unsigned short* __restrict__ kfrag,
    const unsigned short* __restrict__ vt, float* __restrict__ out)
{
    __shared__ unsigned short p_lds[4][16 * 40];     // 5.1 KB
    __shared__ float o_lds[4][16][68];               // 17.4 KB
    __shared__ float l_lds[4][16];

    const int j  = blockIdx.x;
    const int b  = j & 7;
    const int ti = 127 - (j >> 3);                   // heavy tiles first
    const int q0 = ti * 16;

    const int ln   = threadIdx.x & 15;
    const int quad = (threadIdx.x >> 4) & 3;
    const int w    = threadIdx.x >> 6;
    const int lane = threadIdx.x & 63;

    const unsigned short* qb = qbf + (size_t)b * Tn * Hn;
    const unsigned short* Kb = kfrag + (size_t)b * 131072;
    const unsigned short* Vb = vt + (size_t)b * 131072;

    const short8 aq0 = *reinterpret_cast<const short8*>(qb + (size_t)(q0 + ln) * Hn + quad * 8);
    const short8 aq1 = *reinterpret_cast<const short8*>(qb + (size_t)(q0 + ln) * Hn + 32 + quad * 8);

    floatx4 O[4];
    #pragma unroll
    for (int c = 0; c < 4; ++c) O[c] = (floatx4){0.f, 0.f, 0.f, 0.f};
    float lp[4] = {0.f, 0.f, 0.f, 0.f};

    const int ntiles = (q0 + 47) >> 5;
    const int per    = (ntiles + 3) >> 2;
    const int beg    = w * per;
    const int end    = min(beg + per, ntiles);
    unsigned short* pP = p_lds[w];

    short8 kf[4];
    if (beg < end) {
        #pragma unroll
        for (int u = 0; u < 4; ++u)
            kf[u] = *reinterpret_cast<const short8*>(Kb + ((size_t)(beg * 4 + u)) * 512 + lane * 8);
    }

    for (int t = beg; t < end; ++t) {
        const int tn = (t + 1 < end) ? (t + 1) : t;
        short8 kn[4], vf[4];
        #pragma unroll
        for (int u = 0; u < 4; ++u) {
            kn[u] = *reinterpret_cast<const short8*>(Kb + ((size_t)(tn * 4 + u)) * 512 + lane * 8);
            vf[u] = *reinterpret_cast<const short8*>(Vb + ((size_t)(t * 4 + u)) * 512 + lane * 8);
        }

        const floatx4 z = (floatx4){0.f, 0.f, 0.f, 0.f};
        floatx4 S[2];
        #pragma unroll
        for (int s = 0; s < 2; ++s) {
            S[s] = __builtin_amdgcn_mfma_f32_16x16x32_bf16(aq0, kf[s * 2], z, 0, 0, 0);
            S[s] = __builtin_amdgcn_mfma_f32_16x16x32_bf16(aq1, kf[s * 2 + 1], S[s], 0, 0, 0);
        }

        const bool diag = (t == ntiles - 1);
        #pragma unroll
        for (int s = 0; s < 2; ++s) {
            #pragma unroll
            for (int r = 0; r < 4; ++r) {
                float sv = S[s][r];
                if (diag && (t * 32 + s * 16 + ln > q0 + quad * 4 + r)) sv = -1e30f;
                const unsigned int pu = __float_as_uint(exp2f(sv));
                lp[r] += __uint_as_float(pu & 0xffff0000u);
                pP[(quad * 4 + r) * 40 + s * 16 + ln] = (unsigned short)(pu >> 16);
            }
        }
        __asm__ volatile("s_waitcnt lgkmcnt(0)" ::: "memory");
        const short8 pa = *reinterpret_cast<const short8*>(pP + ln * 40 + quad * 8);
        #pragma unroll
        for (int c = 0; c < 4; ++c)
            O[c] = __builtin_amdgcn_mfma_f32_16x16x32_bf16(pa, vf[c], O[c], 0, 0, 0);
        #pragma unroll
        for (int u = 0; u < 4; ++u) kf[u] = kn[u];
    }

    #pragma unroll
    for (int c = 0; c < 4; ++c)
        #pragma unroll
        for (int r = 0; r < 4; ++r)
            o_lds[w][quad * 4 + r][c * 16 + ln] = O[c][r];
    #pragma unroll
    for (int r = 0; r < 4; ++r) {
        const float ls = rsum16(lp[r]);
        if (ln == 0) l_lds[w][quad * 4 + r] = ls;
    }
    __syncthreads();

    const int qq = threadIdx.x >> 4;
    const int dg = threadIdx.x & 15;
    const float ltot = l_lds[0][qq] + l_lds[1][qq] + l_lds[2][qq] + l_lds[3][qq];
    const float inv = 1.0f / ltot;
    const float4 a0 = *reinterpret_cast<float4*>(&o_lds[0][qq][dg * 4]);
    const float4 a1 = *reinterpret_cast<float4*>(&o_lds[1][qq][dg * 4]);
    const float4 a2 = *reinterpret_cast<float4*>(&o_lds[2][qq][dg * 4]);
    const float4 a3 = *reinterpret_cast<float4*>(&o_lds[3][qq][dg * 4]);
    float4 r;
    r.x = (a0.x + a1.x + a2.x + a3.x) * inv;
    r.y = (a0.y + a1.y + a2.y + a3.y) * inv;
    r.z = (a0.z + a1.z + a2.z + a3.z) * inv;
    r.w = (a0.w + a1.w + a2.w + a3.w) * inv;
    *reinterpret_cast<float4*>(out + ((size_t)b * Tn + q0 + qq) * Hn + dg * 4) = r;
}

// ---------------------------------------------------------------------------
extern "C" void kernel_launch(void* const* d_in, const int* in_sizes, int n_in,
                              void* d_out, int out_size, void* d_ws, size_t ws_size,
                              hipStream_t stream) {
    (void)in_sizes; (void)n_in; (void)out_size; (void)ws_size;
    const float* x  = (const float*)d_in[0];
    const float* Wq = (const float*)d_in[1];
    const float* Wk = (const float*)d_in[2];
    const float* Wv = (const float*)d_in[3];
    float* out = (float*)d_out;

    unsigned short* Wfrag = (unsigned short*)d_ws;            // 196608
    unsigned short* qbf   = Wfrag + (size_t)196608;           // 1048576
    unsigned short* kfr   = qbf + (size_t)Bn * Tn * Hn;       // 1048576
    unsigned short* vfr   = kfr + (size_t)Bn * 131072;        // 1048576

    prep_w<<<96, 256, 0, stream>>>(Wq, Wk, Wv, Wfrag);
    proj_mfma<<<(Bn * Tn) / 16, 256, 0, stream>>>(x, Wfrag, qbf, kfr, vfr);
    attn_mfma<<<Bn * (Tn / 16), 256, 0, stream>>>(qbf, kfr, vfr, out);
}

// Round 4
// 124.384 us; speedup vs baseline: 1.0115x; 1.0025x over previous
//
#include <hip/hip_runtime.h>
#include <hip/hip_bf16.h>
#include <math.h>

#define Bn 8
#define Tn 2048
#define Cn 1024
#define Hn 64

typedef __attribute__((ext_vector_type(8))) short short8;
typedef __attribute__((ext_vector_type(4))) float floatx4;

#define ATTN_SCALE 0.18033688011112042f   // log2(e) / sqrt(64)

__device__ inline unsigned short f2bf(float f) {
    union { float f; unsigned int u; } x; x.f = f;
    unsigned int r = x.u + 0x7fffu + ((x.u >> 16) & 1u);
    return (unsigned short)(r >> 16);
}

__device__ inline uint2 pack4bf(float4 v) {
    __hip_bfloat162 lo = __float22bfloat162_rn(make_float2(v.x, v.y));
    __hip_bfloat162 hi = __float22bfloat162_rn(make_float2(v.z, v.w));
    uint2 r;
    r.x = *reinterpret_cast<unsigned int*>(&lo);
    r.y = *reinterpret_cast<unsigned int*>(&hi);
    return r;
}

__device__ inline float rsum16(float v) {
    v += __shfl_xor(v, 1);
    v += __shfl_xor(v, 2);
    v += __shfl_xor(v, 4);
    v += __shfl_xor(v, 8);
    return v;
}

// ---------------------------------------------------------------------------
// Kernel 0: W -> bf16 in MFMA B-FRAGMENT ORDER.  (unchanged, verified)
// ---------------------------------------------------------------------------
__global__ __launch_bounds__(256) void prep_w(
    const float* __restrict__ Wq, const float* __restrict__ Wk,
    const float* __restrict__ Wv, unsigned short* __restrict__ Wfrag)
{
    const int gid = blockIdx.x * 256 + threadIdx.x;   // 0..24575
    const int c    = gid >> 11;
    const int rem  = gid & 2047;
    const int ks   = rem >> 6;
    const int lane = rem & 63;
    const int ln = lane & 15, qd = lane >> 4;
    const int mat = c >> 2, nc = c & 3;
    const float* W = (mat == 0) ? Wq : (mat == 1) ? Wk : Wv;
    const float sc = (mat == 0) ? ATTN_SCALE : 1.0f;
    const int col = nc * 16 + ln;
    unsigned short o[8];
    #pragma unroll
    for (int j = 0; j < 8; ++j)
        o[j] = f2bf(W[(size_t)(ks * 32 + qd * 8 + j) * Hn + col] * sc);
    *reinterpret_cast<short8*>(Wfrag + (size_t)gid * 8) = *reinterpret_cast<short8*>(o);
}

// ---------------------------------------------------------------------------
// Kernel 1: fused QKV projection — SINGLE-STAGE LDS, BARRIER-FREE COMPUTE.
// (byte-identical to verified round-0/round-3 state)
// ---------------------------------------------------------------------------
__global__ __launch_bounds__(256, 4) void proj_mfma(
    const float* __restrict__ x, const unsigned short* __restrict__ Wfrag,
    unsigned short* __restrict__ qbf, unsigned short* __restrict__ kfrag,
    unsigned short* __restrict__ vfrag)
{
    __shared__ unsigned short xs[32 * 512];     // 32 KB

    const int ln   = threadIdx.x & 15;
    const int quad = (threadIdx.x >> 4) & 3;
    const int w    = threadIdx.x >> 6;
    const int lane = threadIdx.x & 63;
    const int row0 = blockIdx.x * 16;

    // ---- phase 1: stage x tile ----
    const int srow = threadIdx.x >> 4;          // 0..15
    const int sf   = threadIdx.x & 15;          // f4 slot base
    const float4* xrow4 = reinterpret_cast<const float4*>(x + (size_t)(row0 + srow) * Cn);

    float4 ld[16];
    #pragma unroll
    for (int it = 0; it < 16; ++it)
        ld[it] = xrow4[sf + 16 * it];
    #pragma unroll
    for (int it = 0; it < 16; ++it) {
        const int f4g = sf + 16 * it;
        const int s = f4g >> 3;
        const int q = (f4g >> 1) & 3;
        const int j = (f4g & 1) * 4;
        *reinterpret_cast<uint2*>(&xs[s * 512 + (q * 16 + srow) * 8 + j]) = pack4bf(ld[it]);
    }
    __syncthreads();

    // ---- phase 2: barrier-free MFMA stream ----
    floatx4 acc[3];
    #pragma unroll
    for (int i = 0; i < 3; ++i) acc[i] = (floatx4){0.f, 0.f, 0.f, 0.f};

    #pragma unroll 4
    for (int s = 0; s < 32; ++s) {
        const short8 a = *reinterpret_cast<const short8*>(&xs[s * 512 + lane * 8]);
        #pragma unroll
        for (int i = 0; i < 3; ++i) {
            const int cc = w * 3 + i;
            const short8 b = *reinterpret_cast<const short8*>(
                Wfrag + ((size_t)(cc * 32 + s) * 64 + lane) * 8);
            acc[i] = __builtin_amdgcn_mfma_f32_16x16x32_bf16(a, b, acc[i], 0, 0, 0);
        }
    }

    // epilogue: C layout col = ln, row = quad*4 + r   (verified, idx = w*3+i)
    const int t0   = row0 + quad * 4;
    const int b    = t0 >> 11;
    const int tloc = t0 & 2047;
    #pragma unroll
    for (int i = 0; i < 3; ++i) {
        const int idx = w * 3 + i;
        const int mat = idx >> 2, ch = idx & 3;
        if (mat == 0) {
            #pragma unroll
            for (int r = 0; r < 4; ++r)
                qbf[(size_t)(t0 + r) * Hn + ch * 16 + ln] = f2bf(acc[i][r]);
        } else if (mat == 1) {
            const int kc = tloc >> 4;
            const int ks = ch >> 1;
            const int lq = (ch & 1) * 2 + (ln >> 3);
            #pragma unroll
            for (int r = 0; r < 4; ++r) {
                const int lanep = (quad * 4 + r) + 16 * lq;
                kfrag[(((size_t)(b * 128 + kc) * 2 + ks) * 64 + lanep) * 8 + (ln & 7)]
                    = f2bf(acc[i][r]);
            }
        } else {
            const int kb32 = tloc >> 5;
            const int off  = t0 & 31;
            const int qd   = off >> 3;
            const int j0   = off & 7;
            const int lanep = ln + 16 * qd;
            ushort4 pk;
            pk.x = f2bf(acc[i][0]); pk.y = f2bf(acc[i][1]);
            pk.z = f2bf(acc[i][2]); pk.w = f2bf(acc[i][3]);
            *reinterpret_cast<ushort4*>(
                vfrag + (((size_t)(b * 64 + kb32) * 4 + ch) * 64 + lanep) * 8 + j0) = pk;
        }
    }
}

// ---------------------------------------------------------------------------
// Kernel 2: causal flash attention.  Body byte-identical to verified round-0;
// ONLY the block->q-tile mapping changed: constant per-CU 4-sum bijection.
// CU c holds blocks {c, c+256, c+512, c+768} -> jj = {u, u+32, u+64, u+96};
// ti(jj): g=jj>>5, u=jj&31 -> {127-u, 64+u, 63-u, u}; per-CU work sum = 254
// for EVERY CU (round-0 mapping ranged 192..316 -> 1.24x critical-path slack).
// Heavy tiles still dispatched first.
// ---------------------------------------------------------------------------
__global__ __launch_bounds__(256, 4) void attn_mfma(
    const unsigned short* __restrict__ qbf, const unsigned short* __restrict__ kfrag,
    const unsigned short* __restrict__ vt, float* __restrict__ out)
{
    __shared__ unsigned short p_lds[4][16 * 40];     // 5.1 KB
    __shared__ float o_lds[4][16][68];               // 17.4 KB
    __shared__ float l_lds[4][16];

    const int j  = blockIdx.x;
    const int b  = j & 7;
    const int jj = j >> 3;                           // 0..127
    const int g  = jj >> 5;
    const int u  = jj & 31;
    const int ti = (g == 0) ? (127 - u) : (g == 1) ? (64 + u)
                 : (g == 2) ? (63 - u)  : u;         // balanced 4-sum bijection
    const int q0 = ti * 16;

    const int ln   = threadIdx.x & 15;
    const int quad = (threadIdx.x >> 4) & 3;
    const int w    = threadIdx.x >> 6;
    const int lane = threadIdx.x & 63;

    const unsigned short* qb = qbf + (size_t)b * Tn * Hn;
    const unsigned short* Kb = kfrag + (size_t)b * 131072;
    const unsigned short* Vb = vt + (size_t)b * 131072;

    const short8 aq0 = *reinterpret_cast<const short8*>(qb + (size_t)(q0 + ln) * Hn + quad * 8);
    const short8 aq1 = *reinterpret_cast<const short8*>(qb + (size_t)(q0 + ln) * Hn + 32 + quad * 8);

    floatx4 O[4];
    #pragma unroll
    for (int c = 0; c < 4; ++c) O[c] = (floatx4){0.f, 0.f, 0.f, 0.f};
    float lp[4] = {0.f, 0.f, 0.f, 0.f};

    const int ntiles = (q0 + 47) >> 5;
    const int per    = (ntiles + 3) >> 2;
    const int beg    = w * per;
    const int end    = min(beg + per, ntiles);
    unsigned short* pP = p_lds[w];

    short8 kf[4];
    if (beg < end) {
        #pragma unroll
        for (int u2 = 0; u2 < 4; ++u2)
            kf[u2] = *reinterpret_cast<const short8*>(Kb + ((size_t)(beg * 4 + u2)) * 512 + lane * 8);
    }

    for (int t = beg; t < end; ++t) {
        const int tn = (t + 1 < end) ? (t + 1) : t;
        short8 kn[4], vf[4];
        #pragma unroll
        for (int u2 = 0; u2 < 4; ++u2) {
            kn[u2] = *reinterpret_cast<const short8*>(Kb + ((size_t)(tn * 4 + u2)) * 512 + lane * 8);
            vf[u2] = *reinterpret_cast<const short8*>(Vb + ((size_t)(t * 4 + u2)) * 512 + lane * 8);
        }

        const floatx4 z = (floatx4){0.f, 0.f, 0.f, 0.f};
        floatx4 S[2];
        #pragma unroll
        for (int s = 0; s < 2; ++s) {
            S[s] = __builtin_amdgcn_mfma_f32_16x16x32_bf16(aq0, kf[s * 2], z, 0, 0, 0);
            S[s] = __builtin_amdgcn_mfma_f32_16x16x32_bf16(aq1, kf[s * 2 + 1], S[s], 0, 0, 0);
        }

        const bool diag = (t == ntiles - 1);
        #pragma unroll
        for (int s = 0; s < 2; ++s) {
            #pragma unroll
            for (int r = 0; r < 4; ++r) {
                float sv = S[s][r];
                if (diag && (t * 32 + s * 16 + ln > q0 + quad * 4 + r)) sv = -1e30f;
                const unsigned int pu = __float_as_uint(exp2f(sv));
                lp[r] += __uint_as_float(pu & 0xffff0000u);
                pP[(quad * 4 + r) * 40 + s * 16 + ln] = (unsigned short)(pu >> 16);
            }
        }
        __asm__ volatile("s_waitcnt lgkmcnt(0)" ::: "memory");
        const short8 pa = *reinterpret_cast<const short8*>(pP + ln * 40 + quad * 8);
        #pragma unroll
        for (int c = 0; c < 4; ++c)
            O[c] = __builtin_amdgcn_mfma_f32_16x16x32_bf16(pa, vf[c], O[c], 0, 0, 0);
        #pragma unroll
        for (int u2 = 0; u2 < 4; ++u2) kf[u2] = kn[u2];
    }

    #pragma unroll
    for (int c = 0; c < 4; ++c)
        #pragma unroll
        for (int r = 0; r < 4; ++r)
            o_lds[w][quad * 4 + r][c * 16 + ln] = O[c][r];
    #pragma unroll
    for (int r = 0; r < 4; ++r) {
        const float ls = rsum16(lp[r]);
        if (ln == 0) l_lds[w][quad * 4 + r] = ls;
    }
    __syncthreads();

    const int qq = threadIdx.x >> 4;
    const int dg = threadIdx.x & 15;
    const float ltot = l_lds[0][qq] + l_lds[1][qq] + l_lds[2][qq] + l_lds[3][qq];
    const float inv = 1.0f / ltot;
    const float4 a0 = *reinterpret_cast<float4*>(&o_lds[0][qq][dg * 4]);
    const float4 a1 = *reinterpret_cast<float4*>(&o_lds[1][qq][dg * 4]);
    const float4 a2 = *reinterpret_cast<float4*>(&o_lds[2][qq][dg * 4]);
    const float4 a3 = *reinterpret_cast<float4*>(&o_lds[3][qq][dg * 4]);
    float4 r;
    r.x = (a0.x + a1.x + a2.x + a3.x) * inv;
    r.y = (a0.y + a1.y + a2.y + a3.y) * inv;
    r.z = (a0.z + a1.z + a2.z + a3.z) * inv;
    r.w = (a0.w + a1.w + a2.w + a3.w) * inv;
    *reinterpret_cast<float4*>(out + ((size_t)b * Tn + q0 + qq) * Hn + dg * 4) = r;
}

// ---------------------------------------------------------------------------
extern "C" void kernel_launch(void* const* d_in, const int* in_sizes, int n_in,
                              void* d_out, int out_size, void* d_ws, size_t ws_size,
                              hipStream_t stream) {
    (void)in_sizes; (void)n_in; (void)out_size; (void)ws_size;
    const float* x  = (const float*)d_in[0];
    const float* Wq = (const float*)d_in[1];
    const float* Wk = (const float*)d_in[2];
    const float* Wv = (const float*)d_in[3];
    float* out = (float*)d_out;

    unsigned short* Wfrag = (unsigned short*)d_ws;            // 196608
    unsigned short* qbf   = Wfrag + (size_t)196608;           // 1048576
    unsigned short* kfr   = qbf + (size_t)Bn * Tn * Hn;       // 1048576
    unsigned short* vfr   = kfr + (size_t)Bn * 131072;        // 1048576

    prep_w<<<96, 256, 0, stream>>>(Wq, Wk, Wv, Wfrag);
    proj_mfma<<<(Bn * Tn) / 16, 256, 0, stream>>>(x, Wfrag, qbf, kfr, vfr);
    attn_mfma<<<Bn * (Tn / 16), 256, 0, stream>>>(qbf, kfr, vfr, out);
}